// Round 16
// baseline (729.280 us; speedup 1.0000x reference)
//
#include <hip/hip_runtime.h>

// Problem constants (fixed by reference)
#define R_   3
#define N_   50000
#define E_   400000
#define IN_  128
#define HID_ 64
#define C_   40
#define H_   3
#define NEG_SLOPE 0.2f

// bucketed CSR build: 128 nodes per bucket, fixed slot capacity
#define NB   391        // ceil(N/128)
#define BCAP 2048       // slots per bucket (mean 1024, +32 sigma headroom)

typedef _Float16 half_t;
typedef _Float16 f16x8 __attribute__((ext_vector_type(8)));
typedef _Float16 f16x4 __attribute__((ext_vector_type(4)));
typedef float float4v __attribute__((ext_vector_type(4)));

template <int V> struct vecT;
template <> struct vecT<4> { typedef f16x4 type; };
template <> struct vecT<8> { typedef f16x8 type; };

// ---------------- fused prep: cast feat, transpose W1/W2, zero bucket counters --
__global__ __launch_bounds__(256) void prep_kernel(
        const float* __restrict__ feat, const float* __restrict__ W1,
        const float* __restrict__ W2, half_t* __restrict__ featH,
        half_t* __restrict__ W1t, half_t* __restrict__ W2t,
        int* __restrict__ bcnt) {
    const int nCast = N_ * IN_ / 4;
    const int nW1 = R_ * IN_ * (H_ * HID_);
    const int nW2 = R_ * HID_ * (H_ * C_);
    const int nBC = R_ * NB;
    int idx = blockIdx.x * 256 + threadIdx.x;
    if (idx < nCast) {
        float4 v = ((const float4*)feat)[idx];
        f16x4 h;
        h[0] = (half_t)v.x; h[1] = (half_t)v.y;
        h[2] = (half_t)v.z; h[3] = (half_t)v.w;
        ((f16x4*)featH)[idx] = h;
        return;
    }
    idx -= nCast;
    if (idx < nW1) {
        const int K = IN_, Nc = H_ * HID_;
        int r = idx / (K * Nc), rem = idx - r * K * Nc;
        int n = rem / K, k = rem - n * K;
        W1t[idx] = (half_t)W1[((size_t)r * K + k) * Nc + n];
        return;
    }
    idx -= nW1;
    if (idx < nW2) {
        const int K = HID_, Nc = H_ * C_;
        int r = idx / (K * Nc), rem = idx - r * K * Nc;
        int n = rem / K, k = rem - n * K;
        W2t[idx] = (half_t)W2[((size_t)r * K + k) * Nc + n];
        return;
    }
    idx -= nW2;
    if (idx < nBC) bcnt[idx] = 0;
}

// ---------------- pass 1: scatter edges into dst-buckets (L2-local writes) ------
__global__ void scatter_kernel(const int* __restrict__ src, const int* __restrict__ dst,
                               int* __restrict__ bcnt, int2* __restrict__ ebuf) {
    int idx = blockIdx.x * 256 + threadIdx.x;
    if (idx < R_ * E_) {
        int r = idx / E_;
        int s = src[idx], d = dst[idx];
        int rb = r * NB + (d >> 7);
        int slot = atomicAdd(&bcnt[rb], 1) & (BCAP - 1);
        ebuf[(size_t)rb * BCAP + slot] = make_int2(s, d);
    }
}

// ---------------- pass 2: per-bucket CSR build (LDS int atomics, wave scan) -----
// One block per (bucket, relation): stage edges in LDS, count per node, scan,
// write sstart/send + place srcs into contiguous bucket span of csr2.
__global__ __launch_bounds__(256) void build_kernel(
        const int* __restrict__ bcnt, const int2* __restrict__ ebuf,
        int* __restrict__ csr2, int* __restrict__ sstart, int* __restrict__ send) {
    int b = blockIdx.x, r = blockIdx.y;
    int rb = r * NB + b;
    int ne = bcnt[rb]; if (ne > BCAP) ne = BCAP;
    int base = b << 7;
    int bufBase = rb * BCAP;
    __shared__ int cnt[128], pre[128], cur[128];
    __shared__ int2 stage[BCAP];
    int tid = threadIdx.x;
    if (tid < 128) { cnt[tid] = 0; cur[tid] = 0; }
    __syncthreads();
    for (int e = tid; e < ne; e += 256) {
        int2 p = ebuf[bufBase + e];
        stage[e] = p;
        atomicAdd(&cnt[p.y - base], 1);        // native ds_add (int)
    }
    __syncthreads();
    if (tid < 64) {
        int c0 = cnt[2 * tid], c1 = cnt[2 * tid + 1];
        int s = c0 + c1;
        int run = s;
        #pragma unroll
        for (int off = 1; off < 64; off <<= 1) {
            int x = __shfl_up(run, off);
            if (tid >= off) run += x;
        }
        int excl = run - s;
        pre[2 * tid] = excl;
        pre[2 * tid + 1] = excl + c0;
        int n0 = base + 2 * tid, n1 = n0 + 1;
        if (n0 < N_) {
            sstart[r * N_ + n0] = bufBase + excl;
            send[r * N_ + n0]   = bufBase + excl + c0;
        }
        if (n1 < N_) {
            sstart[r * N_ + n1] = bufBase + excl + c0;
            send[r * N_ + n1]   = bufBase + excl + c0 + c1;
        }
    }
    // zero 4 slack slots so guarded over-reads (ii beyond ee) see a valid node 0
    if (tid < 4 && ne + tid < BCAP) csr2[bufBase + ne + tid] = 0;
    __syncthreads();
    for (int e = tid; e < ne; e += 256) {
        int2 p = stage[e];
        int local = p.y - base;
        int pos = atomicAdd(&cur[local], 1);
        csr2[bufBase + pre[local] + pos] = p.x;
    }
}

// ---------------- MFMA GEMM: Z[r] = A @ Bt[r]^T (row stride = Nc) ----------------
template <int K>
__global__ __launch_bounds__(256) void mfma_gemm_kernel(
        const half_t* __restrict__ A, const half_t* __restrict__ Bt,
        half_t* __restrict__ Z, int M, int Nc) {
    int r = blockIdx.z;
    int wave = threadIdx.x >> 6, lane = threadIdx.x & 63;
    int lrow = lane & 15, lq = lane >> 4;
    int rowA = blockIdx.x * 64 + wave * 16 + lrow;
    int col0 = blockIdx.y * 64;
    const half_t* Btr = Bt + (size_t)r * Nc * K;
    const half_t* aP = A + (size_t)rowA * K + lq * 8;
    bool arow_ok = (rowA < M);
    f16x8 zv8 = {};
    float4v acc[4] = {};
    #pragma unroll
    for (int k0 = 0; k0 < K; k0 += 32) {
        f16x8 af = arow_ok ? *(const f16x8*)(aP + k0) : zv8;
        #pragma unroll
        for (int ct = 0; ct < 4; ++ct) {
            int col = col0 + ct * 16 + lrow;
            f16x8 bf = (col < Nc) ? *(const f16x8*)(Btr + (size_t)col * K + lq * 8 + k0) : zv8;
            acc[ct] = __builtin_amdgcn_mfma_f32_16x16x32_f16(af, bf, acc[ct], 0, 0, 0);
        }
    }
    half_t* Zr = Z + (size_t)r * N_ * Nc;
    int rbase = blockIdx.x * 64 + wave * 16 + lq * 4;
    #pragma unroll
    for (int ct = 0; ct < 4; ++ct) {
        int col = col0 + ct * 16 + lrow;
        if (col >= Nc) continue;
        #pragma unroll
        for (int g = 0; g < 4; ++g) {
            int row = rbase + g;
            if (row < M) Zr[(size_t)row * Nc + col] = (half_t)acc[ct][g];
        }
    }
}

// ---------------- attention logits: one THREAD per (r,n,h), no shuffles ----
template <int Dd>
__global__ __launch_bounds__(256) void attn2_kernel(
        const half_t* __restrict__ z, const float* __restrict__ al,
        const float* __restrict__ ar, float* __restrict__ el,
        float* __restrict__ er) {
    int t = blockIdx.x * 256 + threadIdx.x;
    if (t >= R_ * N_ * H_) return;
    int rn = t / H_, h = t - rn * H_;
    int r = rn / N_;
    const half_t* zrow = z + (size_t)rn * (3 * Dd) + h * Dd;
    const float* alp = al + (r * H_ + h) * Dd;
    const float* arp = ar + (r * H_ + h) * Dd;
    float p0 = 0.f, p1 = 0.f, q0 = 0.f, q1 = 0.f;
    #pragma unroll
    for (int c = 0; c < Dd / 8; ++c) {
        f16x8 zv = *(const f16x8*)(zrow + c * 8);
        #pragma unroll
        for (int j = 0; j < 8; j += 2) {
            float za = (float)zv[j], zb = (float)zv[j + 1];
            p0 += za * alp[c * 8 + j];
            p1 += zb * alp[c * 8 + j + 1];
            q0 += za * arp[c * 8 + j];
            q1 += zb * arp[c * 8 + j + 1];
        }
    }
    el[t] = p0 + p1;
    er[t] = q0 + q1;
}

// ---------------- fused softmax + gather + aggregate (round-14 agg12 + abs CSR) -
// One wave per node, 3 relations interleaved (loads issued back-to-back for
// MLP), split-wave (2 edges per wave instr), no-max softmax, pk-fp16 accum,
// guarded ragged ends (c=0, safe index). sstart/send give absolute positions
// into csr2. Plain coalesced store.
template <int Dd, int VEC, bool RELU, typename OutT>
__global__ __launch_bounds__(256) void agg14_kernel(
        const int* __restrict__ sstart, const int* __restrict__ send,
        const int* __restrict__ csr2, const half_t* __restrict__ z,
        const float* __restrict__ el, const float* __restrict__ er,
        const float* __restrict__ bias, OutT* __restrict__ out, float scale) {
    constexpr int ROWH = 3 * Dd;
    constexpr int LPE  = ROWH / VEC;    // 30 / 24
    constexpr int PH   = Dd / VEC;      // 10 / 8
    using fv = typename vecT<VEC>::type;
    int n = blockIdx.x * 4 + (threadIdx.x >> 6);
    int lane = threadIdx.x & 63;
    if (n >= N_) return;
    int hf = lane >> 5;
    int sub = lane & 31;
    bool act = sub < LPE;
    int hl = act ? sub / PH : 0;
    int dl = act ? sub - hl * PH : 0;
    int zoff = VEC * sub;
    int ii[R_], ee[R_], i0[R_];
    float ervv[R_];
    #pragma unroll
    for (int r = 0; r < R_; ++r) {
        ii[r] = sstart[r * N_ + n];
        ee[r] = send[r * N_ + n];
        i0[r] = ii[r];
        ervv[r] = er[((size_t)r * N_ + n) * H_ + hl];
    }
    fv ah[R_] = {};
    float ll[R_] = {};
    while (ii[0] < ee[0] || ii[1] < ee[1] || ii[2] < ee[2]) {
        fv zA[R_], zB[R_];
        float xA[R_], xB[R_];
        bool okA[R_], okB[R_];
        #pragma unroll
        for (int r = 0; r < R_; ++r) {
            const half_t* zr = z + (size_t)r * N_ * ROWH;
            const float* elr = el + (size_t)r * N_ * H_;
            int eA = ii[r] + hf, eB = ii[r] + 2 + hf;
            okA[r] = eA < ee[r];
            okB[r] = eB < ee[r];
            int sA = csr2[okA[r] ? eA : i0[r]];
            int sB = csr2[okB[r] ? eB : i0[r]];
            xA[r] = elr[sA * H_ + hl] + ervv[r];
            xB[r] = elr[sB * H_ + hl] + ervv[r];
            zA[r] = {}; zB[r] = {};
            if (act) {
                zA[r] = *(const fv*)(zr + sA * ROWH + zoff);
                zB[r] = *(const fv*)(zr + sB * ROWH + zoff);
            }
        }
        #pragma unroll
        for (int r = 0; r < R_; ++r) {
            float xa = xA[r]; xa = fmaxf(xa, NEG_SLOPE * xa);
            float xb = xB[r]; xb = fmaxf(xb, NEG_SLOPE * xb);
            float cA = okA[r] ? __expf(xa) : 0.f;
            float cB = okB[r] ? __expf(xb) : 0.f;
            ll[r] += cA + cB;
            half_t hA = (half_t)cA, hB = (half_t)cB;
            fv vA, vB;
            #pragma unroll
            for (int v = 0; v < VEC; ++v) { vA[v] = hA; vB[v] = hB; }
            ah[r] += vA * zA[r] + vB * zB[r];   // v_pk_fma_f16
        }
        #pragma unroll
        for (int r = 0; r < R_; ++r) ii[r] += 4;
    }
    // ---- epilogue: cvt once, cross-half combine (l replicated per head group) --
    float aa[R_][VEC];
    #pragma unroll
    for (int r = 0; r < R_; ++r)
        #pragma unroll
        for (int v = 0; v < VEC; ++v) aa[r][v] = (float)ah[r][v];
    #pragma unroll
    for (int r = 0; r < R_; ++r) {
        #pragma unroll
        for (int v = 0; v < VEC; ++v) aa[r][v] += __shfl(aa[r][v], lane ^ 32);
        ll[r] += __shfl(ll[r], lane ^ 32);
    }
    float vacc[VEC] = {};
    #pragma unroll
    for (int r = 0; r < R_; ++r) {
        float li = (ll[r] > 0.f) ? 1.f / ll[r] : 0.f;
        const float* br = bias + r * ROWH + hl * Dd + VEC * dl;
        #pragma unroll
        for (int v = 0; v < VEC; ++v) {
            float t = aa[r][v] * li + br[v];
            if (RELU) t = fmaxf(t, 0.f);
            vacc[v] += t;
        }
    }
    int base = lane & 32;
    int p1 = sub + PH;     if (p1 >= LPE) p1 -= LPE;
    int p2 = sub + 2 * PH; if (p2 >= LPE) p2 -= LPE;
    #pragma unroll
    for (int v = 0; v < VEC; ++v)
        vacc[v] += __shfl(vacc[v], base + p1) + __shfl(vacc[v], base + p2);
    int srcl = lane / VEC;
    int cm = lane & (VEC - 1);
    float tv[VEC];
    #pragma unroll
    for (int v = 0; v < VEC; ++v) tv[v] = __shfl(vacc[v], srcl);
    float outv = tv[0];
    #pragma unroll
    for (int v = 1; v < VEC; ++v) outv = (cm == v) ? tv[v] : outv;
    if (lane < Dd) out[(size_t)n * Dd + lane] = (OutT)(outv * scale);
}

// ---------------- launch ----------------
static inline size_t align256(size_t x) { return (x + 255) & ~(size_t)255; }

extern "C" void kernel_launch(void* const* d_in, const int* in_sizes, int n_in,
                              void* d_out, int out_size, void* d_ws, size_t ws_size,
                              hipStream_t stream) {
    const float* feat = (const float*)d_in[0];
    const int*   src  = (const int*)d_in[1];
    const int*   dst  = (const int*)d_in[2];
    const float* W1   = (const float*)d_in[3];
    const float* al1  = (const float*)d_in[4];
    const float* ar1  = (const float*)d_in[5];
    const float* b1   = (const float*)d_in[6];
    const float* W2   = (const float*)d_in[7];
    const float* al2  = (const float*)d_in[8];
    const float* ar2  = (const float*)d_in[9];
    const float* b2   = (const float*)d_in[10];
    float* out = (float*)d_out;

    // workspace carve
    char* ws = (char*)d_ws;
    size_t off = 0;
    half_t* zbuf = (half_t*)(ws + off); off += align256((size_t)R_ * N_ * (3 * HID_) * 2);
    half_t* featH = (half_t*)(ws + off); off += align256((size_t)N_ * IN_ * 2);
    half_t* h1h  = (half_t*)(ws + off); off += align256((size_t)N_ * HID_ * 2);
    half_t* W1t  = (half_t*)(ws + off); off += align256((size_t)R_ * (H_ * HID_) * IN_ * 2);
    half_t* W2t  = (half_t*)(ws + off); off += align256((size_t)R_ * (H_ * C_) * HID_ * 2);
    float* el   = (float*)(ws + off); off += align256((size_t)R_ * N_ * H_ * 4);
    float* er   = (float*)(ws + off); off += align256((size_t)R_ * N_ * H_ * 4);
    int* bcnt   = (int*)(ws + off);   off += align256((size_t)R_ * NB * 4);
    int2* ebuf  = (int2*)(ws + off);  off += align256((size_t)R_ * NB * BCAP * 8);
    int* csr2   = (int*)(ws + off);   off += align256((size_t)R_ * NB * BCAP * 4);
    int* sstart = (int*)(ws + off);   off += align256((size_t)R_ * N_ * 4);
    int* send   = (int*)(ws + off);   off += align256((size_t)R_ * N_ * 4);
    (void)ws_size; (void)n_in; (void)in_sizes; (void)out_size;

    const int EDGE_BLOCKS = (R_ * E_ + 255) / 256;     // 4688
    const int ROW_TILES = (N_ + 63) / 64;              // 782
    const int NODE_WAVES = (N_ + 3) / 4;               // 12500
    const int ATTN_BLOCKS = (R_ * N_ * H_ + 255) / 256;// 1758
    const int PREP_ITEMS = N_ * IN_ / 4 + R_ * IN_ * (H_ * HID_)
                         + R_ * HID_ * (H_ * C_) + R_ * NB;
    const int PREP_BLOCKS = (PREP_ITEMS + 255) / 256;

    // ---- prep (cast, transposes, zero bucket counters) ----
    prep_kernel<<<PREP_BLOCKS, 256, 0, stream>>>(feat, W1, W2, featH, W1t, W2t, bcnt);
    // ---- CSR build: bucketed two-pass (L2-local writes, no amplification) ----
    scatter_kernel<<<EDGE_BLOCKS, 256, 0, stream>>>(src, dst, bcnt, ebuf);
    build_kernel<<<dim3(NB, R_), 256, 0, stream>>>(bcnt, ebuf, csr2, sstart, send);

    // ---- layer 1: IN -> H*HID, relu; agg writes h1h (fp16) directly ----
    mfma_gemm_kernel<IN_><<<dim3(ROW_TILES, 3, R_), 256, 0, stream>>>(
        featH, W1t, zbuf, N_, H_ * HID_);
    attn2_kernel<HID_><<<ATTN_BLOCKS, 256, 0, stream>>>(zbuf, al1, ar1, el, er);
    agg14_kernel<HID_, 8, true, half_t><<<NODE_WAVES, 256, 0, stream>>>(
        sstart, send, csr2, zbuf, el, er, b1, h1h, 1.f / (H_ * R_));

    // ---- layer 2: HID -> H*C, no relu; agg writes d_out (fp32) directly ----
    mfma_gemm_kernel<HID_><<<dim3(ROW_TILES, 2, R_), 256, 0, stream>>>(
        h1h, W2t, zbuf, N_, H_ * C_);
    attn2_kernel<C_><<<ATTN_BLOCKS, 256, 0, stream>>>(zbuf, al2, ar2, el, er);
    agg14_kernel<C_, 4, false, float><<<NODE_WAVES, 256, 0, stream>>>(
        sstart, send, csr2, zbuf, el, er, b2, out, 1.f / (H_ * R_));
}